// Round 10
// baseline (31.783 us; speedup 1.0000x reference)
//
#include <hip/hip_runtime.h>
#include <hip/hip_bf16.h>
#include <math.h>

// R10: R8's proven batched-scalar staging, 64-px strips, 5 blocks/CU.
// R8 (128px, 3 blk/CU) = 27.1us total. R9 (dwordx4 + 4blk cap128) regressed
// -> revert staging to scalar batched. This round: strip 128->64 px
// (LDS 16.6KB), 1 subtile/wave, launch_bounds(256,5) -> 5 blocks/CU (62%
// occupancy vs 37%), halves per-barrier staging drain; more overlap partners.

#define ALPHA_F 8.3f

constexpr int B_    = 4;
constexpr int CIN   = 32;
constexpr int COUT  = 32;
constexpr int H_    = 256;
constexpr int W_    = 256;
constexpr int KTAPS = 9;
constexpr int HW    = H_ * W_;

typedef __attribute__((ext_vector_type(8))) short bf16x8;
typedef __attribute__((ext_vector_type(4))) float f32x4;

static __device__ __forceinline__ short f2bf(float f) {
    __hip_bfloat16 h = __float2bfloat16(f);
    return __builtin_bit_cast(short, h);
}

// ---- prep: weights into per-lane A-fragment layout (verified R2-R9) ----
__global__ void prep_wfrag(const float* __restrict__ w, short* __restrict__ wf) {
    int idx = blockIdx.x * 256 + threadIdx.x;
    if (idx >= KTAPS * 2 * 64 * 8) return;
    int e  = idx & 7;
    int l  = (idx >> 3) & 63;
    int t  = (idx >> 9) & 1;
    int ij = idx >> 10;
    int o  = t * 16 + (l & 15);
    int c  = (l >> 4) * 8 + e;
    wf[idx] = f2bf(w[(o * CIN + c) * KTAPS + ij]);
}

// ---- fused main kernel: 64-px strip ----
__global__ __launch_bounds__(256, 5)
void dconv_fused6(const float* __restrict__ x,
                  const float* __restrict__ depth,
                  const short* __restrict__ wf,
                  float* __restrict__ out) {
    __shared__ __align__(16) short xs[3][66][40];   // 15840 B bf16 x tile
    __shared__ float dsh[3][66];                    //   792 B depth stencil

    const int bid   = (int)blockIdx.x;
    const int strip = (bid & 7) * 512 + (bid >> 3); // XCD-bijective swizzle
    const int b     = strip >> 10;                  // 1024 strips per image
    const int h     = (strip >> 2) & 255;
    const int wseg  = (strip & 3) << 6;             // 64-px segment base
    const int tid   = threadIdx.x;
    const float* xb  = x + (size_t)b * CIN * HW;
    const float* dpl = depth + (size_t)b * HW;

    // ========== PHASE A: issue ALL global loads (batched) ==========
    // x main: 3 rows x 16 ch-pairs x 64 px = 3072 pairs, 12/thread
    float xv0[12], xv1[12];
#pragma unroll
    for (int it = 0; it < 12; ++it) {
        const int idx = it * 256 + tid;
        const int q   = idx & 63;
        const int cp  = (idx >> 6) & 15;
        const int r   = idx >> 10;
        const int row = h + r - 1;
        const int rowc = ((unsigned)row < (unsigned)H_) ? row : h;  // clamp
        const size_t gb = (size_t)(2 * cp) * HW + rowc * W_ + wseg + q;
        xv0[it] = xb[gb];
        xv1[it] = xb[gb + HW];
    }
    // halo columns: 2 edge px x 3 rows x 16 ch-pairs (threads 0..95)
    float hv0, hv1;
    {
        const int side = tid & 1;
        const int hrc  = tid >> 1;
        const int hcp  = hrc & 15;
        const int hr   = (hrc >> 4) % 3;
        const int hrow = h + hr - 1;
        const int hwx  = wseg - 1 + side * 65;
        const bool hok = (tid < 96) &&
                         ((unsigned)hrow < (unsigned)H_) &&
                         ((unsigned)hwx  < (unsigned)W_);
        const size_t gb = (size_t)(2 * hcp) * HW +
                          (hok ? (size_t)(hrow * W_ + hwx) : 0);
        hv0 = xb[gb];
        hv1 = xb[gb + HW];
    }
    // depth stencil: 3 x 66 = 198 values (threads 0..197)
    float dv0;
    {
        const int r0   = (tid < 198) ? (tid / 66) : 0;
        const int q0   = (tid < 198) ? (tid - r0 * 66) : 0;
        const int row0 = h + r0 - 1;
        const int wx0  = wseg - 1 + q0;
        const bool ok0 = ((unsigned)row0 < (unsigned)H_) &&
                         ((unsigned)wx0  < (unsigned)W_);
        dv0 = dpl[ok0 ? (row0 * W_ + wx0) : 0];
    }

    // ========== PHASE B: convert + LDS writes ==========
#pragma unroll
    for (int it = 0; it < 12; ++it) {
        const int idx = it * 256 + tid;
        const int q   = idx & 63;
        const int cp  = (idx >> 6) & 15;
        const int r   = idx >> 10;
        const bool ok = ((unsigned)(h + r - 1) < (unsigned)H_);
        const float f0 = ok ? xv0[it] : 0.f;
        const float f1 = ok ? xv1[it] : 0.f;
        const int v = (int)(unsigned short)f2bf(f0) |
                      ((int)(unsigned short)f2bf(f1) << 16);
        ((int*)&xs[r][q + 1][0])[cp] = v;
    }
    if (tid < 96) {
        const int side = tid & 1;
        const int hrc  = tid >> 1;
        const int hcp  = hrc & 15;
        const int hr   = hrc >> 4;
        const int hrow = h + hr - 1;
        const int hwx  = wseg - 1 + side * 65;
        const bool hok = ((unsigned)hrow < (unsigned)H_) &&
                         ((unsigned)hwx  < (unsigned)W_);
        const float f0 = hok ? hv0 : 0.f;
        const float f1 = hok ? hv1 : 0.f;
        const int v = (int)(unsigned short)f2bf(f0) |
                      ((int)(unsigned short)f2bf(f1) << 16);
        ((int*)&xs[hr][side * 65][0])[hcp] = v;
    }
    if (tid < 198) {
        const int r0   = tid / 66;
        const int q0   = tid - r0 * 66;
        const bool ok0 = ((unsigned)(h + r0 - 1) < (unsigned)H_) &&
                         ((unsigned)(wseg - 1 + q0) < (unsigned)W_);
        dsh[r0][q0] = ok0 ? dv0 : 0.f;
    }
    __syncthreads();

    // ========== compute: 1 subtile per wave ==========
    const int lane = tid & 63;
    const int warp = tid >> 6;
    const int n    = lane & 15;
    const int cg   = (lane >> 4) * 8;
    const int pl   = warp * 16 + n + 1;
    const int wp   = wseg + warp * 16 + n;
    const int pix  = h * W_ + wp;

    const float dc = dsh[1][pl];

    float s[KTAPS];
#pragma unroll
    for (int ij = 0; ij < KTAPS; ++ij) {
        const int di = ij / 3 - 1;
        const int dj = ij % 3 - 1;
        const bool ok = ((unsigned)(h + di) < (unsigned)H_) &&
                        ((unsigned)(wp + dj) < (unsigned)W_);
        s[ij] = ok ? __expf(-ALPHA_F * fabsf(dc - dsh[1 + di][pl + dj])) : 0.f;
    }

    const bf16x8* wfv = (const bf16x8*)wf;
    f32x4 acc0 = {0.f, 0.f, 0.f, 0.f};
    f32x4 acc1 = {0.f, 0.f, 0.f, 0.f};
    const f32x4 z = {0.f, 0.f, 0.f, 0.f};
#pragma unroll
    for (int ij = 0; ij < KTAPS; ++ij) {
        const int di = ij / 3 - 1;
        const int dj = ij % 3 - 1;
        const bf16x8 bfrag = *(const bf16x8*)&xs[1 + di][pl + dj][cg];
        const bf16x8 a0 = wfv[(ij * 2 + 0) * 64 + lane];
        const bf16x8 a1 = wfv[(ij * 2 + 1) * 64 + lane];
        const f32x4 t0 = __builtin_amdgcn_mfma_f32_16x16x32_bf16(a0, bfrag, z, 0, 0, 0);
        const f32x4 t1 = __builtin_amdgcn_mfma_f32_16x16x32_bf16(a1, bfrag, z, 0, 0, 0);
#pragma unroll
        for (int j = 0; j < 4; ++j) {
            acc0[j] = fmaf(s[ij], t0[j], acc0[j]);
            acc1[j] = fmaf(s[ij], t1[j], acc1[j]);
        }
    }

    // ---- epilogue: strided nontemporal stores (proven fast, R7 abl) ----
    const int orow = (lane >> 4) * 4;
    float* ob = out + (size_t)b * COUT * HW + pix;
#pragma unroll
    for (int j = 0; j < 4; ++j) {
        __builtin_nontemporal_store(acc0[j], ob + (size_t)(orow + j) * HW);
        __builtin_nontemporal_store(acc1[j], ob + (size_t)(orow + j + 16) * HW);
    }
}

// ---------- fp32 fallback (R1 kernel) ----------
__global__ __launch_bounds__(256)
void dconv_fallback(const float* __restrict__ x,
                    const float* __restrict__ depth,
                    const float* __restrict__ wgt,
                    float* __restrict__ out) {
    const int w  = threadIdx.x;
    const int bh = blockIdx.x;
    const int b  = bh >> 8;
    const int h  = bh & 255;

    const float* dplane = depth + (size_t)b * HW;
    const float  dc     = dplane[h * W_ + w];

    float acc[COUT];
#pragma unroll
    for (int o = 0; o < COUT; ++o) acc[o] = 0.f;

    const float* xb = x + (size_t)b * CIN * HW;

    for (int i = 0; i < 3; ++i) {
        const int  hh  = h + i - 1;
        const bool okh = ((unsigned)hh < (unsigned)H_);
        for (int j = 0; j < 3; ++j) {
            const int  ww = w + j - 1;
            const bool ok = okh && ((unsigned)ww < (unsigned)W_);
            const int  ij = i * 3 + j;
            const float dpv = ok ? dplane[hh * W_ + ww] : 0.f;
            const float sv  = __expf(-ALPHA_F * fabsf(dc - dpv));
            const int base = hh * W_ + ww;
#pragma unroll
            for (int c = 0; c < CIN; ++c) {
                const float v = (ok ? xb[c * HW + base] : 0.f) * sv;
#pragma unroll
                for (int o = 0; o < COUT; ++o) {
                    acc[o] = fmaf(v, wgt[(o * CIN + c) * KTAPS + ij], acc[o]);
                }
            }
        }
    }

    float* ob = out + ((size_t)b * COUT * H_ + h) * W_ + w;
#pragma unroll
    for (int o = 0; o < COUT; ++o) ob[o * HW] = acc[o];
}

extern "C" void kernel_launch(void* const* d_in, const int* in_sizes, int n_in,
                              void* d_out, int out_size, void* d_ws, size_t ws_size,
                              hipStream_t stream) {
    const float* x     = (const float*)d_in[0];
    const float* depth = (const float*)d_in[1];
    const float* wgt   = (const float*)d_in[2];
    float*       out   = (float*)d_out;

    const size_t wf_bytes = (size_t)(KTAPS * 2 * 64 * 8) * sizeof(short); // 18 KB

    if (ws_size >= wf_bytes) {
        short* wf = (short*)d_ws;
        prep_wfrag<<<(KTAPS * 2 * 64 * 8 + 255) / 256, 256, 0, stream>>>(wgt, wf);
        dconv_fused6<<<4096, 256, 0, stream>>>(x, depth, wf, out);
    } else {
        dconv_fallback<<<B_ * H_, 256, 0, stream>>>(x, depth, wgt, out);
    }
}

// Round 11
// 26.796 us; speedup vs baseline: 1.1861x; 1.1861x over previous
//
#include <hip/hip_runtime.h>
#include <hip/hip_bf16.h>
#include <math.h>

// R11: taller tiles to cut halo re-read traffic.
// R6-R10 ledger: compute ~5us, stores ~free, staging ~20us; occupancy raise
// (R10) didn't help -> staging is traffic-bound (1-row strips re-read every
// x row 3x: ~102MB L2/L3). This round: tile = 4 rows x 64 px (halo 6x66),
// re-read 3.05x -> 1.55x (51MB). Staging keeps R8's PROVEN batched-scalar
// pattern (48 loads, one drain). 1024 blocks = exactly 4/CU co-resident
// (launch_bounds(256,4)); compute is subtile-serial to keep VGPR ~85 << 128
// (R9 lesson: don't hold f32x4 batches near the cap).

#define ALPHA_F 8.3f

constexpr int B_    = 4;
constexpr int CIN   = 32;
constexpr int COUT  = 32;
constexpr int H_    = 256;
constexpr int W_    = 256;
constexpr int KTAPS = 9;
constexpr int HW    = H_ * W_;

typedef __attribute__((ext_vector_type(8))) short bf16x8;
typedef __attribute__((ext_vector_type(4))) float f32x4;

static __device__ __forceinline__ short f2bf(float f) {
    __hip_bfloat16 h = __float2bfloat16(f);
    return __builtin_bit_cast(short, h);
}

// ---- prep: weights into per-lane A-fragment layout (verified R2-R10) ----
__global__ void prep_wfrag(const float* __restrict__ w, short* __restrict__ wf) {
    int idx = blockIdx.x * 256 + threadIdx.x;
    if (idx >= KTAPS * 2 * 64 * 8) return;
    int e  = idx & 7;
    int l  = (idx >> 3) & 63;
    int t  = (idx >> 9) & 1;
    int ij = idx >> 10;
    int o  = t * 16 + (l & 15);
    int c  = (l >> 4) * 8 + e;
    wf[idx] = f2bf(w[(o * CIN + c) * KTAPS + ij]);
}

// ---- fused main kernel: 4 rows x 64 px tile ----
__global__ __launch_bounds__(256, 4)
void dconv_fused7(const float* __restrict__ x,
                  const float* __restrict__ depth,
                  const short* __restrict__ wf,
                  float* __restrict__ out) {
    __shared__ __align__(16) short xs[6][66][40];   // 31,680 B bf16 x tile
    __shared__ float dsh[6][66];                    //  1,584 B depth stencil

    // XCD-bijective swizzle: 1024 blocks, 1024 % 8 == 0
    const int bid  = (int)blockIdx.x;
    const int bswz = (bid & 7) * 128 + (bid >> 3);

    const int b    = bswz >> 8;          // image (4)
    const int hseg = (bswz >> 2) & 63;   // 64 row-groups
    const int wseg = (bswz & 3) << 6;    // 4 col segments of 64 px
    const int h0   = hseg << 2;          // first output row
    const int tid  = threadIdx.x;
    const float* xb  = x + (size_t)b * CIN * HW;
    const float* dpl = depth + (size_t)b * HW;

    // ========== PHASE A: issue ALL global loads (R8 pattern) ==========
    // x main: 6 rows x 16 ch-pairs x 64 px = 6144 pairs, 24/thread
    float xv0[24], xv1[24];
#pragma unroll
    for (int it = 0; it < 24; ++it) {
        const int idx = it * 256 + tid;
        const int q   = idx & 63;
        const int cp  = (idx >> 6) & 15;
        const int r   = idx >> 10;                   // 0..5
        const int row = h0 + r - 1;
        const int rowc = ((unsigned)row < (unsigned)H_) ? row : h0;  // clamp
        const size_t gb = (size_t)(2 * cp) * HW + rowc * W_ + wseg + q;
        xv0[it] = xb[gb];
        xv1[it] = xb[gb + HW];
    }
    // halo columns: 6 rows x 16 ch-pairs x 2 sides = 192 units (tid<192)
    float hv0, hv1;
    {
        const int side = tid & 1;
        const int hrc  = tid >> 1;                   // 0..95
        const int hcp  = hrc & 15;
        const int hr   = (hrc >> 4) % 6;             // 0..5
        const int hrow = h0 + hr - 1;
        const int hwx  = wseg - 1 + side * 65;
        const bool hok = (tid < 192) &&
                         ((unsigned)hrow < (unsigned)H_) &&
                         ((unsigned)hwx  < (unsigned)W_);
        const size_t gb = (size_t)(2 * hcp) * HW +
                          (hok ? (size_t)(hrow * W_ + hwx) : 0);
        hv0 = xb[gb];
        hv1 = xb[gb + HW];
    }
    // depth stencil: 6 x 66 = 396 values (k = tid, tid+256)
    float dv0, dv1;
    {
        const int r0   = tid / 66;                   // 0..3
        const int q0   = tid - r0 * 66;
        const int row0 = h0 + r0 - 1;
        const int wx0  = wseg - 1 + q0;
        const bool ok0 = ((unsigned)row0 < (unsigned)H_) &&
                         ((unsigned)wx0  < (unsigned)W_);
        dv0 = dpl[ok0 ? (row0 * W_ + wx0) : 0];

        const int k1   = tid + 256;
        const int r1   = (k1 / 66) % 6;
        const int q1   = k1 - (k1 / 66) * 66;
        const int row1 = h0 + r1 - 1;
        const int wx1  = wseg - 1 + q1;
        const bool ok1 = (k1 < 396) &&
                         ((unsigned)row1 < (unsigned)H_) &&
                         ((unsigned)wx1  < (unsigned)W_);
        dv1 = dpl[ok1 ? (row1 * W_ + wx1) : 0];
    }

    // ========== PHASE B: convert + LDS writes ==========
#pragma unroll
    for (int it = 0; it < 24; ++it) {
        const int idx = it * 256 + tid;
        const int q   = idx & 63;
        const int cp  = (idx >> 6) & 15;
        const int r   = idx >> 10;
        const bool ok = ((unsigned)(h0 + r - 1) < (unsigned)H_);
        const float f0 = ok ? xv0[it] : 0.f;
        const float f1 = ok ? xv1[it] : 0.f;
        const int v = (int)(unsigned short)f2bf(f0) |
                      ((int)(unsigned short)f2bf(f1) << 16);
        ((int*)&xs[r][q + 1][0])[cp] = v;
    }
    if (tid < 192) {
        const int side = tid & 1;
        const int hrc  = tid >> 1;
        const int hcp  = hrc & 15;
        const int hr   = hrc >> 4;                   // 0..5
        const int hrow = h0 + hr - 1;
        const int hwx  = wseg - 1 + side * 65;
        const bool hok = ((unsigned)hrow < (unsigned)H_) &&
                         ((unsigned)hwx  < (unsigned)W_);
        const float f0 = hok ? hv0 : 0.f;
        const float f1 = hok ? hv1 : 0.f;
        const int v = (int)(unsigned short)f2bf(f0) |
                      ((int)(unsigned short)f2bf(f1) << 16);
        ((int*)&xs[hr][side * 65][0])[hcp] = v;
    }
    {
        const int r0   = tid / 66;
        const int q0   = tid - r0 * 66;
        const bool ok0 = ((unsigned)(h0 + r0 - 1) < (unsigned)H_) &&
                         ((unsigned)(wseg - 1 + q0) < (unsigned)W_);
        dsh[r0][q0] = ok0 ? dv0 : 0.f;
        const int k1 = tid + 256;
        if (k1 < 396) {
            const int r1   = k1 / 66;
            const int q1   = k1 - r1 * 66;
            const bool ok1 = ((unsigned)(h0 + r1 - 1) < (unsigned)H_) &&
                             ((unsigned)(wseg - 1 + q1) < (unsigned)W_);
            dsh[r1][q1] = ok1 ? dv1 : 0.f;
        }
    }
    __syncthreads();

    // ========== compute: wave w owns output row h0+w; 4 subtiles serial ====
    const int lane = tid & 63;
    const int w    = tid >> 6;           // 0..3
    const int n    = lane & 15;
    const int cg   = (lane >> 4) * 8;
    const int rl   = w + 1;              // local row in halo coords
    const int hrow = h0 + w;             // global output row
    const int orow = (lane >> 4) * 4;
    const bf16x8* wfv = (const bf16x8*)wf;
    const f32x4 z = {0.f, 0.f, 0.f, 0.f};

    for (int sub = 0; sub < 4; ++sub) {
        const int pl = sub * 16 + n + 1;
        const int wp = wseg + sub * 16 + n;
        const float dc = dsh[rl][pl];

        float s[KTAPS];
#pragma unroll
        for (int ij = 0; ij < KTAPS; ++ij) {
            const int di = ij / 3 - 1;
            const int dj = ij % 3 - 1;
            const bool ok = ((unsigned)(hrow + di) < (unsigned)H_) &&
                            ((unsigned)(wp + dj) < (unsigned)W_);
            s[ij] = ok ? __expf(-ALPHA_F * fabsf(dc - dsh[rl + di][pl + dj])) : 0.f;
        }

        f32x4 acc0 = z, acc1 = z;
#pragma unroll
        for (int ij = 0; ij < KTAPS; ++ij) {
            const int di = ij / 3 - 1;
            const int dj = ij % 3 - 1;
            const bf16x8 bfrag = *(const bf16x8*)&xs[rl + di][pl + dj][cg];
            const bf16x8 a0 = wfv[(ij * 2 + 0) * 64 + lane];
            const bf16x8 a1 = wfv[(ij * 2 + 1) * 64 + lane];
            const f32x4 t0 = __builtin_amdgcn_mfma_f32_16x16x32_bf16(a0, bfrag, z, 0, 0, 0);
            const f32x4 t1 = __builtin_amdgcn_mfma_f32_16x16x32_bf16(a1, bfrag, z, 0, 0, 0);
#pragma unroll
            for (int j = 0; j < 4; ++j) {
                acc0[j] = fmaf(s[ij], t0[j], acc0[j]);
                acc1[j] = fmaf(s[ij], t1[j], acc1[j]);
            }
        }

        float* ob = out + (size_t)b * COUT * HW + hrow * W_ + wp;
#pragma unroll
        for (int j = 0; j < 4; ++j) {
            __builtin_nontemporal_store(acc0[j], ob + (size_t)(orow + j) * HW);
            __builtin_nontemporal_store(acc1[j], ob + (size_t)(orow + j + 16) * HW);
        }
    }
}

// ---------- fp32 fallback (R1 kernel) ----------
__global__ __launch_bounds__(256)
void dconv_fallback(const float* __restrict__ x,
                    const float* __restrict__ depth,
                    const float* __restrict__ wgt,
                    float* __restrict__ out) {
    const int w  = threadIdx.x;
    const int bh = blockIdx.x;
    const int b  = bh >> 8;
    const int h  = bh & 255;

    const float* dplane = depth + (size_t)b * HW;
    const float  dc     = dplane[h * W_ + w];

    float acc[COUT];
#pragma unroll
    for (int o = 0; o < COUT; ++o) acc[o] = 0.f;

    const float* xb = x + (size_t)b * CIN * HW;

    for (int i = 0; i < 3; ++i) {
        const int  hh  = h + i - 1;
        const bool okh = ((unsigned)hh < (unsigned)H_);
        for (int j = 0; j < 3; ++j) {
            const int  ww = w + j - 1;
            const bool ok = okh && ((unsigned)ww < (unsigned)W_);
            const int  ij = i * 3 + j;
            const float dpv = ok ? dplane[hh * W_ + ww] : 0.f;
            const float sv  = __expf(-ALPHA_F * fabsf(dc - dpv));
            const int base = hh * W_ + ww;
#pragma unroll
            for (int c = 0; c < CIN; ++c) {
                const float v = (ok ? xb[c * HW + base] : 0.f) * sv;
#pragma unroll
                for (int o = 0; o < COUT; ++o) {
                    acc[o] = fmaf(v, wgt[(o * CIN + c) * KTAPS + ij], acc[o]);
                }
            }
        }
    }

    float* ob = out + ((size_t)b * COUT * H_ + h) * W_ + w;
#pragma unroll
    for (int o = 0; o < COUT; ++o) ob[o * HW] = acc[o];
}

extern "C" void kernel_launch(void* const* d_in, const int* in_sizes, int n_in,
                              void* d_out, int out_size, void* d_ws, size_t ws_size,
                              hipStream_t stream) {
    const float* x     = (const float*)d_in[0];
    const float* depth = (const float*)d_in[1];
    const float* wgt   = (const float*)d_in[2];
    float*       out   = (float*)d_out;

    const size_t wf_bytes = (size_t)(KTAPS * 2 * 64 * 8) * sizeof(short); // 18 KB

    if (ws_size >= wf_bytes) {
        short* wf = (short*)d_ws;
        prep_wfrag<<<(KTAPS * 2 * 64 * 8 + 255) / 256, 256, 0, stream>>>(wgt, wf);
        dconv_fused7<<<1024, 256, 0, stream>>>(x, depth, wf, out);
    } else {
        dconv_fallback<<<B_ * H_, 256, 0, stream>>>(x, depth, wgt, out);
    }
}

// Round 12
// 25.976 us; speedup vs baseline: 1.2235x; 1.0316x over previous
//
#include <hip/hip_runtime.h>
#include <hip/hip_bf16.h>
#include <math.h>

// R12: hoist wf A-fragments to registers (batched in Phase A) + unrolled
// subtile loop. Ledger correction: R6/R7 "absent from top-5" only bounded
// ablations <~40us profiled; total-decomposition gives compute-phase ~20us,
// dominated by 18 wf global loads PER SUBTILE chained into the tap loop
// (72 VMEM loads/wave in R11). Fix: load all 18 bf16x8 wf frags once in
// Phase A (72 VGPR), unroll the 4-subtile loop, launch_bounds(256,3).

#define ALPHA_F 8.3f

constexpr int B_    = 4;
constexpr int CIN   = 32;
constexpr int COUT  = 32;
constexpr int H_    = 256;
constexpr int W_    = 256;
constexpr int KTAPS = 9;
constexpr int HW    = H_ * W_;

typedef __attribute__((ext_vector_type(8))) short bf16x8;
typedef __attribute__((ext_vector_type(4))) float f32x4;

static __device__ __forceinline__ short f2bf(float f) {
    __hip_bfloat16 h = __float2bfloat16(f);
    return __builtin_bit_cast(short, h);
}

// ---- prep: weights into per-lane A-fragment layout (verified R2-R11) ----
__global__ void prep_wfrag(const float* __restrict__ w, short* __restrict__ wf) {
    int idx = blockIdx.x * 256 + threadIdx.x;
    if (idx >= KTAPS * 2 * 64 * 8) return;
    int e  = idx & 7;
    int l  = (idx >> 3) & 63;
    int t  = (idx >> 9) & 1;
    int ij = idx >> 10;
    int o  = t * 16 + (l & 15);
    int c  = (l >> 4) * 8 + e;
    wf[idx] = f2bf(w[(o * CIN + c) * KTAPS + ij]);
}

// ---- fused main kernel: 4 rows x 64 px tile, wf in registers ----
__global__ __launch_bounds__(256, 3)
void dconv_fused8(const float* __restrict__ x,
                  const float* __restrict__ depth,
                  const short* __restrict__ wf,
                  float* __restrict__ out) {
    __shared__ __align__(16) short xs[6][66][40];   // 31,680 B bf16 x tile
    __shared__ float dsh[6][66];                    //  1,584 B depth stencil

    // XCD-bijective swizzle: 1024 blocks, 1024 % 8 == 0
    const int bid  = (int)blockIdx.x;
    const int bswz = (bid & 7) * 128 + (bid >> 3);

    const int b    = bswz >> 8;          // image (4)
    const int hseg = (bswz >> 2) & 63;   // 64 row-groups
    const int wseg = (bswz & 3) << 6;    // 4 col segments of 64 px
    const int h0   = hseg << 2;          // first output row
    const int tid  = threadIdx.x;
    const int lane = tid & 63;
    const float* xb  = x + (size_t)b * CIN * HW;
    const float* dpl = depth + (size_t)b * HW;

    // ========== PHASE A: issue ALL global loads (batched) ==========
    // wf A-fragments: 18 x bf16x8 (72 VGPR), wave-shared, L1-hot
    const bf16x8* wfv = (const bf16x8*)wf;
    bf16x8 wa[2 * KTAPS];
#pragma unroll
    for (int k = 0; k < 2 * KTAPS; ++k) wa[k] = wfv[k * 64 + lane];

    // x main: 6 rows x 16 ch-pairs x 64 px = 6144 pairs, 24/thread
    float xv0[24], xv1[24];
#pragma unroll
    for (int it = 0; it < 24; ++it) {
        const int idx = it * 256 + tid;
        const int q   = idx & 63;
        const int cp  = (idx >> 6) & 15;
        const int r   = idx >> 10;                   // 0..5
        const int row = h0 + r - 1;
        const int rowc = ((unsigned)row < (unsigned)H_) ? row : h0;  // clamp
        const size_t gb = (size_t)(2 * cp) * HW + rowc * W_ + wseg + q;
        xv0[it] = xb[gb];
        xv1[it] = xb[gb + HW];
    }
    // halo columns: 6 rows x 16 ch-pairs x 2 sides = 192 units (tid<192)
    float hv0, hv1;
    {
        const int side = tid & 1;
        const int hrc  = tid >> 1;                   // 0..95
        const int hcp  = hrc & 15;
        const int hr   = (hrc >> 4) % 6;             // 0..5
        const int hrow = h0 + hr - 1;
        const int hwx  = wseg - 1 + side * 65;
        const bool hok = (tid < 192) &&
                         ((unsigned)hrow < (unsigned)H_) &&
                         ((unsigned)hwx  < (unsigned)W_);
        const size_t gb = (size_t)(2 * hcp) * HW +
                          (hok ? (size_t)(hrow * W_ + hwx) : 0);
        hv0 = xb[gb];
        hv1 = xb[gb + HW];
    }
    // depth stencil: 6 x 66 = 396 values (k = tid, tid+256)
    float dv0, dv1;
    {
        const int r0   = tid / 66;                   // 0..3
        const int q0   = tid - r0 * 66;
        const int row0 = h0 + r0 - 1;
        const int wx0  = wseg - 1 + q0;
        const bool ok0 = ((unsigned)row0 < (unsigned)H_) &&
                         ((unsigned)wx0  < (unsigned)W_);
        dv0 = dpl[ok0 ? (row0 * W_ + wx0) : 0];

        const int k1   = tid + 256;
        const int r1   = (k1 / 66) % 6;
        const int q1   = k1 - (k1 / 66) * 66;
        const int row1 = h0 + r1 - 1;
        const int wx1  = wseg - 1 + q1;
        const bool ok1 = (k1 < 396) &&
                         ((unsigned)row1 < (unsigned)H_) &&
                         ((unsigned)wx1  < (unsigned)W_);
        dv1 = dpl[ok1 ? (row1 * W_ + wx1) : 0];
    }

    // ========== PHASE B: convert + LDS writes ==========
#pragma unroll
    for (int it = 0; it < 24; ++it) {
        const int idx = it * 256 + tid;
        const int q   = idx & 63;
        const int cp  = (idx >> 6) & 15;
        const int r   = idx >> 10;
        const bool ok = ((unsigned)(h0 + r - 1) < (unsigned)H_);
        const float f0 = ok ? xv0[it] : 0.f;
        const float f1 = ok ? xv1[it] : 0.f;
        const int v = (int)(unsigned short)f2bf(f0) |
                      ((int)(unsigned short)f2bf(f1) << 16);
        ((int*)&xs[r][q + 1][0])[cp] = v;
    }
    if (tid < 192) {
        const int side = tid & 1;
        const int hrc  = tid >> 1;
        const int hcp  = hrc & 15;
        const int hr   = hrc >> 4;                   // 0..5
        const int hrow = h0 + hr - 1;
        const int hwx  = wseg - 1 + side * 65;
        const bool hok = ((unsigned)hrow < (unsigned)H_) &&
                         ((unsigned)hwx  < (unsigned)W_);
        const float f0 = hok ? hv0 : 0.f;
        const float f1 = hok ? hv1 : 0.f;
        const int v = (int)(unsigned short)f2bf(f0) |
                      ((int)(unsigned short)f2bf(f1) << 16);
        ((int*)&xs[hr][side * 65][0])[hcp] = v;
    }
    {
        const int r0   = tid / 66;
        const int q0   = tid - r0 * 66;
        const bool ok0 = ((unsigned)(h0 + r0 - 1) < (unsigned)H_) &&
                         ((unsigned)(wseg - 1 + q0) < (unsigned)W_);
        dsh[r0][q0] = ok0 ? dv0 : 0.f;
        const int k1 = tid + 256;
        if (k1 < 396) {
            const int r1   = k1 / 66;
            const int q1   = k1 - r1 * 66;
            const bool ok1 = ((unsigned)(h0 + r1 - 1) < (unsigned)H_) &&
                             ((unsigned)(wseg - 1 + q1) < (unsigned)W_);
            dsh[r1][q1] = ok1 ? dv1 : 0.f;
        }
    }
    __syncthreads();

    // ========== compute: wave w owns output row h0+w; 4 subtiles UNROLLED ==
    const int w    = tid >> 6;           // 0..3
    const int n    = lane & 15;
    const int cg   = (lane >> 4) * 8;
    const int rl   = w + 1;              // local row in halo coords
    const int hrow = h0 + w;             // global output row
    const int orow = (lane >> 4) * 4;
    const f32x4 z = {0.f, 0.f, 0.f, 0.f};

#pragma unroll
    for (int sub = 0; sub < 4; ++sub) {
        const int pl = sub * 16 + n + 1;
        const int wp = wseg + sub * 16 + n;
        const float dc = dsh[rl][pl];

        float s[KTAPS];
#pragma unroll
        for (int ij = 0; ij < KTAPS; ++ij) {
            const int di = ij / 3 - 1;
            const int dj = ij % 3 - 1;
            const bool ok = ((unsigned)(hrow + di) < (unsigned)H_) &&
                            ((unsigned)(wp + dj) < (unsigned)W_);
            s[ij] = ok ? __expf(-ALPHA_F * fabsf(dc - dsh[rl + di][pl + dj])) : 0.f;
        }

        f32x4 acc0 = z, acc1 = z;
#pragma unroll
        for (int ij = 0; ij < KTAPS; ++ij) {
            const int di = ij / 3 - 1;
            const int dj = ij % 3 - 1;
            const bf16x8 bfrag = *(const bf16x8*)&xs[rl + di][pl + dj][cg];
            const f32x4 t0 = __builtin_amdgcn_mfma_f32_16x16x32_bf16(wa[ij * 2 + 0], bfrag, z, 0, 0, 0);
            const f32x4 t1 = __builtin_amdgcn_mfma_f32_16x16x32_bf16(wa[ij * 2 + 1], bfrag, z, 0, 0, 0);
#pragma unroll
            for (int j = 0; j < 4; ++j) {
                acc0[j] = fmaf(s[ij], t0[j], acc0[j]);
                acc1[j] = fmaf(s[ij], t1[j], acc1[j]);
            }
        }

        float* ob = out + (size_t)b * COUT * HW + hrow * W_ + wp;
#pragma unroll
        for (int j = 0; j < 4; ++j) {
            __builtin_nontemporal_store(acc0[j], ob + (size_t)(orow + j) * HW);
            __builtin_nontemporal_store(acc1[j], ob + (size_t)(orow + j + 16) * HW);
        }
    }
}

// ---------- fp32 fallback (R1 kernel) ----------
__global__ __launch_bounds__(256)
void dconv_fallback(const float* __restrict__ x,
                    const float* __restrict__ depth,
                    const float* __restrict__ wgt,
                    float* __restrict__ out) {
    const int w  = threadIdx.x;
    const int bh = blockIdx.x;
    const int b  = bh >> 8;
    const int h  = bh & 255;

    const float* dplane = depth + (size_t)b * HW;
    const float  dc     = dplane[h * W_ + w];

    float acc[COUT];
#pragma unroll
    for (int o = 0; o < COUT; ++o) acc[o] = 0.f;

    const float* xb = x + (size_t)b * CIN * HW;

    for (int i = 0; i < 3; ++i) {
        const int  hh  = h + i - 1;
        const bool okh = ((unsigned)hh < (unsigned)H_);
        for (int j = 0; j < 3; ++j) {
            const int  ww = w + j - 1;
            const bool ok = okh && ((unsigned)ww < (unsigned)W_);
            const int  ij = i * 3 + j;
            const float dpv = ok ? dplane[hh * W_ + ww] : 0.f;
            const float sv  = __expf(-ALPHA_F * fabsf(dc - dpv));
            const int base = hh * W_ + ww;
#pragma unroll
            for (int c = 0; c < CIN; ++c) {
                const float v = (ok ? xb[c * HW + base] : 0.f) * sv;
#pragma unroll
                for (int o = 0; o < COUT; ++o) {
                    acc[o] = fmaf(v, wgt[(o * CIN + c) * KTAPS + ij], acc[o]);
                }
            }
        }
    }

    float* ob = out + ((size_t)b * COUT * H_ + h) * W_ + w;
#pragma unroll
    for (int o = 0; o < COUT; ++o) ob[o * HW] = acc[o];
}

extern "C" void kernel_launch(void* const* d_in, const int* in_sizes, int n_in,
                              void* d_out, int out_size, void* d_ws, size_t ws_size,
                              hipStream_t stream) {
    const float* x     = (const float*)d_in[0];
    const float* depth = (const float*)d_in[1];
    const float* wgt   = (const float*)d_in[2];
    float*       out   = (float*)d_out;

    const size_t wf_bytes = (size_t)(KTAPS * 2 * 64 * 8) * sizeof(short); // 18 KB

    if (ws_size >= wf_bytes) {
        short* wf = (short*)d_ws;
        prep_wfrag<<<(KTAPS * 2 * 64 * 8 + 255) / 256, 256, 0, stream>>>(wgt, wf);
        dconv_fused8<<<1024, 256, 0, stream>>>(x, depth, wf, out);
    } else {
        dconv_fallback<<<B_ * H_, 256, 0, stream>>>(x, depth, wgt, out);
    }
}

// Round 13
// 24.122 us; speedup vs baseline: 1.3176x; 1.0769x over previous
//
#include <hip/hip_runtime.h>
#include <hip/hip_bf16.h>
#include <math.h>

// R13: R12 structure, but exactly ONE residency generation.
// Plateau analysis R8-R12: 1024 blocks @ 3 blocks/CU = two generations
// (768+256), second gen at 25% utilization -> ~1.5x makespan inflation.
// Fix: launch_bounds(256,4) -> 4 blocks/CU, all 1024 blocks co-resident.
// Register fit at the 128 cap (R9/R10 spill lesson): wa[18] hoist moved to
// AFTER Phase-B LDS writes (independent of LDS; drain overlaps barrier), so
// Phase A/B peak ~70 VGPR, compute peak ~110 -- both under 128.

#define ALPHA_F 8.3f

constexpr int B_    = 4;
constexpr int CIN   = 32;
constexpr int COUT  = 32;
constexpr int H_    = 256;
constexpr int W_    = 256;
constexpr int KTAPS = 9;
constexpr int HW    = H_ * W_;

typedef __attribute__((ext_vector_type(8))) short bf16x8;
typedef __attribute__((ext_vector_type(4))) float f32x4;

static __device__ __forceinline__ short f2bf(float f) {
    __hip_bfloat16 h = __float2bfloat16(f);
    return __builtin_bit_cast(short, h);
}

// ---- prep: weights into per-lane A-fragment layout (verified R2-R12) ----
__global__ void prep_wfrag(const float* __restrict__ w, short* __restrict__ wf) {
    int idx = blockIdx.x * 256 + threadIdx.x;
    if (idx >= KTAPS * 2 * 64 * 8) return;
    int e  = idx & 7;
    int l  = (idx >> 3) & 63;
    int t  = (idx >> 9) & 1;
    int ij = idx >> 10;
    int o  = t * 16 + (l & 15);
    int c  = (l >> 4) * 8 + e;
    wf[idx] = f2bf(w[(o * CIN + c) * KTAPS + ij]);
}

// ---- fused main kernel: 4 rows x 64 px tile, single residency generation --
__global__ __launch_bounds__(256, 4)
void dconv_fused9(const float* __restrict__ x,
                  const float* __restrict__ depth,
                  const short* __restrict__ wf,
                  float* __restrict__ out) {
    __shared__ __align__(16) short xs[6][66][40];   // 31,680 B bf16 x tile
    __shared__ float dsh[6][66];                    //  1,584 B depth stencil

    // XCD-bijective swizzle: 1024 blocks, 1024 % 8 == 0
    const int bid  = (int)blockIdx.x;
    const int bswz = (bid & 7) * 128 + (bid >> 3);

    const int b    = bswz >> 8;          // image (4)
    const int hseg = (bswz >> 2) & 63;   // 64 row-groups
    const int wseg = (bswz & 3) << 6;    // 4 col segments of 64 px
    const int h0   = hseg << 2;          // first output row
    const int tid  = threadIdx.x;
    const int lane = tid & 63;
    const float* xb  = x + (size_t)b * CIN * HW;
    const float* dpl = depth + (size_t)b * HW;

    // ========== PHASE A: issue ALL x/depth loads (batched) ==========
    // x main: 6 rows x 16 ch-pairs x 64 px = 6144 pairs, 24/thread
    float xv0[24], xv1[24];
#pragma unroll
    for (int it = 0; it < 24; ++it) {
        const int idx = it * 256 + tid;
        const int q   = idx & 63;
        const int cp  = (idx >> 6) & 15;
        const int r   = idx >> 10;                   // 0..5
        const int row = h0 + r - 1;
        const int rowc = ((unsigned)row < (unsigned)H_) ? row : h0;  // clamp
        const size_t gb = (size_t)(2 * cp) * HW + rowc * W_ + wseg + q;
        xv0[it] = xb[gb];
        xv1[it] = xb[gb + HW];
    }
    // halo columns: 6 rows x 16 ch-pairs x 2 sides = 192 units (tid<192)
    float hv0, hv1;
    {
        const int side = tid & 1;
        const int hrc  = tid >> 1;                   // 0..95
        const int hcp  = hrc & 15;
        const int hr   = (hrc >> 4) % 6;             // 0..5
        const int hrow = h0 + hr - 1;
        const int hwx  = wseg - 1 + side * 65;
        const bool hok = (tid < 192) &&
                         ((unsigned)hrow < (unsigned)H_) &&
                         ((unsigned)hwx  < (unsigned)W_);
        const size_t gb = (size_t)(2 * hcp) * HW +
                          (hok ? (size_t)(hrow * W_ + hwx) : 0);
        hv0 = xb[gb];
        hv1 = xb[gb + HW];
    }
    // depth stencil: 6 x 66 = 396 values (k = tid, tid+256)
    float dv0, dv1;
    {
        const int r0   = tid / 66;                   // 0..3
        const int q0   = tid - r0 * 66;
        const int row0 = h0 + r0 - 1;
        const int wx0  = wseg - 1 + q0;
        const bool ok0 = ((unsigned)row0 < (unsigned)H_) &&
                         ((unsigned)wx0  < (unsigned)W_);
        dv0 = dpl[ok0 ? (row0 * W_ + wx0) : 0];

        const int k1   = tid + 256;
        const int r1   = (k1 / 66) % 6;
        const int q1   = k1 - (k1 / 66) * 66;
        const int row1 = h0 + r1 - 1;
        const int wx1  = wseg - 1 + q1;
        const bool ok1 = (k1 < 396) &&
                         ((unsigned)row1 < (unsigned)H_) &&
                         ((unsigned)wx1  < (unsigned)W_);
        dv1 = dpl[ok1 ? (row1 * W_ + wx1) : 0];
    }

    // ========== PHASE B: convert + LDS writes ==========
#pragma unroll
    for (int it = 0; it < 24; ++it) {
        const int idx = it * 256 + tid;
        const int q   = idx & 63;
        const int cp  = (idx >> 6) & 15;
        const int r   = idx >> 10;
        const bool ok = ((unsigned)(h0 + r - 1) < (unsigned)H_);
        const float f0 = ok ? xv0[it] : 0.f;
        const float f1 = ok ? xv1[it] : 0.f;
        const int v = (int)(unsigned short)f2bf(f0) |
                      ((int)(unsigned short)f2bf(f1) << 16);
        ((int*)&xs[r][q + 1][0])[cp] = v;
    }
    if (tid < 192) {
        const int side = tid & 1;
        const int hrc  = tid >> 1;
        const int hcp  = hrc & 15;
        const int hr   = hrc >> 4;                   // 0..5
        const int hrow = h0 + hr - 1;
        const int hwx  = wseg - 1 + side * 65;
        const bool hok = ((unsigned)hrow < (unsigned)H_) &&
                         ((unsigned)hwx  < (unsigned)W_);
        const float f0 = hok ? hv0 : 0.f;
        const float f1 = hok ? hv1 : 0.f;
        const int v = (int)(unsigned short)f2bf(f0) |
                      ((int)(unsigned short)f2bf(f1) << 16);
        ((int*)&xs[hr][side * 65][0])[hcp] = v;
    }
    {
        const int r0   = tid / 66;
        const int q0   = tid - r0 * 66;
        const bool ok0 = ((unsigned)(h0 + r0 - 1) < (unsigned)H_) &&
                         ((unsigned)(wseg - 1 + q0) < (unsigned)W_);
        dsh[r0][q0] = ok0 ? dv0 : 0.f;
        const int k1 = tid + 256;
        if (k1 < 396) {
            const int r1   = k1 / 66;
            const int q1   = k1 - r1 * 66;
            const bool ok1 = ((unsigned)(h0 + r1 - 1) < (unsigned)H_) &&
                             ((unsigned)(wseg - 1 + q1) < (unsigned)W_);
            dsh[r1][q1] = ok1 ? dv1 : 0.f;
        }
    }

    // wf A-fragments: issued AFTER staging regs die, drain overlaps barrier.
    const bf16x8* wfv = (const bf16x8*)wf;
    bf16x8 wa[2 * KTAPS];
#pragma unroll
    for (int k = 0; k < 2 * KTAPS; ++k) wa[k] = wfv[k * 64 + lane];

    __syncthreads();

    // ========== compute: wave w owns output row h0+w; 4 subtiles ==========
    const int w    = tid >> 6;           // 0..3
    const int n    = lane & 15;
    const int cg   = (lane >> 4) * 8;
    const int rl   = w + 1;              // local row in halo coords
    const int hrow = h0 + w;             // global output row
    const int orow = (lane >> 4) * 4;
    const f32x4 z = {0.f, 0.f, 0.f, 0.f};

#pragma unroll
    for (int sub = 0; sub < 4; ++sub) {
        const int pl = sub * 16 + n + 1;
        const int wp = wseg + sub * 16 + n;
        const float dc = dsh[rl][pl];

        float s[KTAPS];
#pragma unroll
        for (int ij = 0; ij < KTAPS; ++ij) {
            const int di = ij / 3 - 1;
            const int dj = ij % 3 - 1;
            const bool ok = ((unsigned)(hrow + di) < (unsigned)H_) &&
                            ((unsigned)(wp + dj) < (unsigned)W_);
            s[ij] = ok ? __expf(-ALPHA_F * fabsf(dc - dsh[rl + di][pl + dj])) : 0.f;
        }

        f32x4 acc0 = z, acc1 = z;
#pragma unroll
        for (int ij = 0; ij < KTAPS; ++ij) {
            const int di = ij / 3 - 1;
            const int dj = ij % 3 - 1;
            const bf16x8 bfrag = *(const bf16x8*)&xs[rl + di][pl + dj][cg];
            const f32x4 t0 = __builtin_amdgcn_mfma_f32_16x16x32_bf16(wa[ij * 2 + 0], bfrag, z, 0, 0, 0);
            const f32x4 t1 = __builtin_amdgcn_mfma_f32_16x16x32_bf16(wa[ij * 2 + 1], bfrag, z, 0, 0, 0);
#pragma unroll
            for (int j = 0; j < 4; ++j) {
                acc0[j] = fmaf(s[ij], t0[j], acc0[j]);
                acc1[j] = fmaf(s[ij], t1[j], acc1[j]);
            }
        }

        float* ob = out + (size_t)b * COUT * HW + hrow * W_ + wp;
#pragma unroll
        for (int j = 0; j < 4; ++j) {
            __builtin_nontemporal_store(acc0[j], ob + (size_t)(orow + j) * HW);
            __builtin_nontemporal_store(acc1[j], ob + (size_t)(orow + j + 16) * HW);
        }
    }
}

// ---------- fp32 fallback (R1 kernel) ----------
__global__ __launch_bounds__(256)
void dconv_fallback(const float* __restrict__ x,
                    const float* __restrict__ depth,
                    const float* __restrict__ wgt,
                    float* __restrict__ out) {
    const int w  = threadIdx.x;
    const int bh = blockIdx.x;
    const int b  = bh >> 8;
    const int h  = bh & 255;

    const float* dplane = depth + (size_t)b * HW;
    const float  dc     = dplane[h * W_ + w];

    float acc[COUT];
#pragma unroll
    for (int o = 0; o < COUT; ++o) acc[o] = 0.f;

    const float* xb = x + (size_t)b * CIN * HW;

    for (int i = 0; i < 3; ++i) {
        const int  hh  = h + i - 1;
        const bool okh = ((unsigned)hh < (unsigned)H_);
        for (int j = 0; j < 3; ++j) {
            const int  ww = w + j - 1;
            const bool ok = okh && ((unsigned)ww < (unsigned)W_);
            const int  ij = i * 3 + j;
            const float dpv = ok ? dplane[hh * W_ + ww] : 0.f;
            const float sv  = __expf(-ALPHA_F * fabsf(dc - dpv));
            const int base = hh * W_ + ww;
#pragma unroll
            for (int c = 0; c < CIN; ++c) {
                const float v = (ok ? xb[c * HW + base] : 0.f) * sv;
#pragma unroll
                for (int o = 0; o < COUT; ++o) {
                    acc[o] = fmaf(v, wgt[(o * CIN + c) * KTAPS + ij], acc[o]);
                }
            }
        }
    }

    float* ob = out + ((size_t)b * COUT * H_ + h) * W_ + w;
#pragma unroll
    for (int o = 0; o < COUT; ++o) ob[o * HW] = acc[o];
}

extern "C" void kernel_launch(void* const* d_in, const int* in_sizes, int n_in,
                              void* d_out, int out_size, void* d_ws, size_t ws_size,
                              hipStream_t stream) {
    const float* x     = (const float*)d_in[0];
    const float* depth = (const float*)d_in[1];
    const float* wgt   = (const float*)d_in[2];
    float*       out   = (float*)d_out;

    const size_t wf_bytes = (size_t)(KTAPS * 2 * 64 * 8) * sizeof(short); // 18 KB

    if (ws_size >= wf_bytes) {
        short* wf = (short*)d_ws;
        prep_wfrag<<<(KTAPS * 2 * 64 * 8 + 255) / 256, 256, 0, stream>>>(wgt, wf);
        dconv_fused9<<<1024, 256, 0, stream>>>(x, depth, wf, out);
    } else {
        dconv_fallback<<<B_ * H_, 256, 0, stream>>>(x, depth, wgt, out);
    }
}